// Round 10
// baseline (2218.273 us; speedup 1.0000x reference)
//
#include <hip/hip_runtime.h>
#include <hip/hip_bf16.h>

#define BB 32
#define LL 64
#define EE 1024
#define HH 128
#define VV 32000

typedef unsigned short u16;
typedef unsigned long long u64;
typedef __attribute__((ext_vector_type(8))) short bf16x8;
typedef __attribute__((ext_vector_type(8))) unsigned short u16x8;
typedef __attribute__((ext_vector_type(4))) float f32x4;

#define LOG2E 1.4426950408889634f
#define C2T   2.8853900817779268f   // 2*log2(e)

// output element offsets (return order: logits, c_fin, h_fin, alphas)
#define OFF_C ((size_t)BB * LL * VV)
#define OFF_H (OFF_C + (size_t)BB * HH)
#define OFF_A (OFF_H + (size_t)BB * HH)

// ws byte offsets
#define WS_ENCT 0                    // 8,388,608 B u16 encT [b][h][e] C2T-prescaled
#define WS_WREC ((size_t)8388608)    // 131,072 B u16 wrecT [col][k]
#define WS_HS   ((size_t)8519680)    // 524,288 B bf16
#define WS_GX   ((size_t)9043968)    // 4,194,304 B f32
#define WS_PAYU ((size_t)13238272)   // 532,480 B u64 [32][8][2][130]
#define WS_WT   ((size_t)13770752)   // 8,192,000 B u16 w_softT
#define WS_DFL  ((size_t)21962752)   // 4 B detect flag
#define WS_NEED ((size_t)21962756)

#define PAYU_WORDS (32 * 8 * 2 * 130)   // 66,560

__device__ __forceinline__ float bf2f(u16 u) {
    union { unsigned int i; float f; } v; v.i = ((unsigned int)u) << 16; return v.f;
}
__device__ __forceinline__ u16 f2bf(float f) {
    union { float f; unsigned int i; } v; v.f = f;
    unsigned int x = v.i;
    return (u16)((x + 0x7FFFu + ((x >> 16) & 1u)) >> 16);
}
__device__ __forceinline__ float ldf(const void* p, size_t i, int f32) {
    if (f32) return ((const float*)p)[i];
    return bf2f(((const u16*)p)[i]);
}
__device__ __forceinline__ void stout(void* p, size_t i, float v, int f32) {
    if (f32) ((float*)p)[i] = v;
    else ((u16*)p)[i] = f2bf(v);
}
__device__ __forceinline__ float sigm(float x) {
    return __builtin_amdgcn_rcpf(1.f + __builtin_amdgcn_exp2f(-x * LOG2E));
}
__device__ __forceinline__ float tanh_fast(float x) {
    return 1.f - 2.f * __builtin_amdgcn_rcpf(__builtin_amdgcn_exp2f(x * C2T) + 1.f);
}

// ---- payload reset + dtype detection (merged, 1 launch) ------------------
__global__ __launch_bounds__(256) void resetdetect_kernel(
    u64* __restrict__ pay, const unsigned int* __restrict__ w, int* __restrict__ flag)
{
    int i = blockIdx.x * 256 + threadIdx.x;
    if (i < PAYU_WORDS)
        pay[i] = 0ull;
    if (i == 0) {
        int cnt = 0;
        for (int j = 0; j < 256; ++j) {
            float a = fabsf(bf2f((u16)(w[j] & 0xFFFFu)));
            if (a > 1e-4f && a < 0.5f) ++cnt;
        }
        *flag = (cnt > 128) ? 1 : 0;     // 1 => inputs are bf16
    }
}

// ---- wrecT[col][k] = bf16(w_lstm[128+k][col])  (LDS tile transpose) ------
__global__ __launch_bounds__(1024) void prep_wrec(
    const void* __restrict__ w_lstm, u16* __restrict__ wrecT, const int* __restrict__ flagp)
{
    int isf32 = !flagp[0];
    __shared__ u16 tile[32][33];
    int c0 = blockIdx.x * 32;      // gate col 0..511
    int k0 = blockIdx.y * 32;      // k 0..127
    int tx = threadIdx.x & 31, ty = threadIdx.x >> 5;
    tile[ty][tx] = f2bf(ldf(w_lstm, (size_t)(HH + k0 + ty) * 512 + c0 + tx, isf32));
    __syncthreads();
    wrecT[(size_t)(c0 + ty) * 128 + k0 + tx] = tile[tx][ty];
}

// ---- gates_x = w_emb[sent] @ w_lstm[0:128,:] (gather fused) --------------
__global__ __launch_bounds__(256) void gatesx3_kernel(
    const int* __restrict__ sent, const void* __restrict__ w_emb,
    const void* __restrict__ w_lstm, float* __restrict__ gx,
    const int* __restrict__ flagp)
{
    int isf32 = !flagp[0];
    int row0 = blockIdx.x * 16;
    int tid = threadIdx.x;
    __shared__ float xr[16][128];
    for (int i = tid; i < 2048; i += 256) {
        int r = i >> 7, col = i & 127;
        int id = sent[row0 + r];
        xr[r][col] = ldf(w_emb, (size_t)id * HH + col, isf32);
    }
    __syncthreads();
    int c0 = tid, c1 = tid + 256;
    float a0[16], a1[16];
    #pragma unroll
    for (int r = 0; r < 16; ++r) { a0[r] = 0.f; a1[r] = 0.f; }
    for (int kk = 0; kk < 128; ++kk) {
        float w0, w1;
        if (isf32) {
            w0 = ((const float*)w_lstm)[(size_t)kk * 512 + c0];
            w1 = ((const float*)w_lstm)[(size_t)kk * 512 + c1];
        } else {
            w0 = bf2f(((const u16*)w_lstm)[(size_t)kk * 512 + c0]);
            w1 = bf2f(((const u16*)w_lstm)[(size_t)kk * 512 + c1]);
        }
        #pragma unroll
        for (int r = 0; r < 16; ++r) {
            a0[r] += xr[r][kk] * w0;
            a1[r] += xr[r][kk] * w1;
        }
    }
    #pragma unroll
    for (int r = 0; r < 16; ++r) {
        gx[(size_t)(row0 + r) * 512 + c0] = a0[r];
        gx[(size_t)(row0 + r) * 512 + c1] = a1[r];
    }
}

// ---- w_softT = transpose(w_soft) : (VV, HH) bf16 -------------------------
__global__ __launch_bounds__(1024) void transpose_wsoft(
    const void* __restrict__ w_soft, u16* __restrict__ wT, const int* __restrict__ flagp)
{
    int isf32 = !flagp[0];
    __shared__ u16 tile[32][33];
    int n0 = blockIdx.x * 32;
    int k0 = blockIdx.y * 32;
    int tx = threadIdx.x & 31, ty = threadIdx.x >> 5;
    tile[ty][tx] = f2bf(ldf(w_soft, (size_t)(k0 + ty) * VV + n0 + tx, isf32));
    __syncthreads();
    wT[(size_t)(n0 + ty) * HH + k0 + tx] = tile[tx][ty];
}

// ---- encT[b][h][e] = bf16(C2T * (enc[b][e][:] . V_e[:][h])) --------------
__global__ __launch_bounds__(256) void encproj_kernel(
    const void* __restrict__ enc_out, const void* __restrict__ V,
    u16* __restrict__ encT, const int* __restrict__ flagp)
{
    int isf32 = !flagp[0];
    __shared__ float ve[HH][HH];
    int b = blockIdx.y;
    int e0 = blockIdx.x * 64;
    int tid = threadIdx.x;
    for (int i = tid; i < HH * HH; i += 256)
        ve[i >> 7][i & 127] = ldf(V, i, isf32);
    __syncthreads();
    int e = e0 + (tid & 63);
    int hb = (tid >> 6) * 32;
    size_t rowbase = ((size_t)b * EE + e) * HH;
    float acc[32];
    #pragma unroll
    for (int i = 0; i < 32; ++i) acc[i] = 0.f;
    for (int k0 = 0; k0 < HH; k0 += 16) {
        float ef[16];
        #pragma unroll
        for (int i = 0; i < 16; ++i) ef[i] = ldf(enc_out, rowbase + k0 + i, isf32);
        #pragma unroll
        for (int hh = 0; hh < 32; ++hh) {
            float a = acc[hh];
            #pragma unroll
            for (int kk = 0; kk < 16; ++kk)
                a += ef[kk] * ve[k0 + kk][hb + hh];
            acc[hh] = a;
        }
    }
    u16* outp = encT + ((size_t)b * HH) * EE + e;
    #pragma unroll
    for (int hh = 0; hh < 32; ++hh)
        outp[(size_t)(hh + hb) * EE] = f2bf(acc[hh] * C2T);
}

// ---- cooperative scan: 8 blocks per group, TWO batches per group ---------
// Software-pipelined dual-batch schedule: each batch's exchange round-trip
// is hidden under the other batch's compute phases. Per-batch math is
// op-for-op identical to round 9 (validated absmax 0.015625).
// 128 blocks: g = bid&15 (group, 2 batches), k = bid>>4 (partner 0..7).
__global__ __launch_bounds__(1024) void scan_kernel(
    const void* __restrict__ init_c, const void* __restrict__ init_h,
    const void* __restrict__ enc_out, const u16* __restrict__ wrecT,
    const void* __restrict__ V, const u16* __restrict__ encTg16,
    const float* __restrict__ gx, u16* __restrict__ hs_bf,
    void* __restrict__ out, u64* __restrict__ payu,
    const int* __restrict__ flagp)
{
    const int isf32 = !flagp[0];
    const int bid = blockIdx.x;
    const int g = bid & 15, k = bid >> 4;
    const int b0 = g * 2, b1 = g * 2 + 1;
    const int tid = threadIdx.x;

    __shared__ u16   wrecl[512 * 128];         // 128KB bf16 w_rec [col][k] (shared by both batches)
    __shared__ float gp[512];                  // scratch
    __shared__ float harr[2][128], cst[2][128];
    __shared__ float hnew[128], hvC[128];      // scratch
    __shared__ float dred[8][128];             // scratch
    __shared__ float sc[2][128];
    __shared__ float selfp[2][130];
    __shared__ float exch[8][130];             // scratch (poll+combine adjacent)
    __shared__ float redw[2], redw2[2];
    __shared__ float m_sv[2], s_sv[2];

    // ---- one-time staging ----
    for (int i = tid; i < 8192; i += 1024)
        *(u16x8*)&wrecl[i * 8] = *(const u16x8*)&wrecT[(size_t)i * 8];
    if (tid < 128) {
        cst[0][tid]  = ldf(init_c, (size_t)b0 * HH + tid, isf32);
        harr[0][tid] = ldf(init_h, (size_t)b0 * HH + tid, isf32);
        cst[1][tid]  = ldf(init_c, (size_t)b1 * HH + tid, isf32);
        harr[1][tid] = ldf(init_h, (size_t)b1 * HH + tid, isf32);
    }
    __syncthreads();

    // -------- per-batch phase chain A..F + publish (R9-identical math) ----
    auto phases = [&](int s, int b, int t) {
        const unsigned int want = (unsigned int)(t + 1);
        float g0 = 0.f, g1 = 0.f, g2 = 0.f, g3 = 0.f;
        if (tid < 128) {
            const float* gxr = gx + (size_t)(b * LL + t) * 512;
            g0 = gxr[tid]; g1 = gxr[128 + tid]; g2 = gxr[256 + tid]; g3 = gxr[384 + tid];
        }
        // A: all 512 gate cols, replicated; 16 lanes per col
        {
            int kc = tid & 15, colb = tid >> 4;
            #pragma unroll
            for (int it = 0; it < 8; ++it) {
                int col = colb + (it << 6);
                const bf16x8 wv = *(const bf16x8*)&wrecl[col * 128 + kc * 8];
                float acc = 0.f;
                #pragma unroll
                for (int j = 0; j < 8; ++j)
                    acc = __builtin_fmaf(harr[s][kc * 8 + j], bf2f((u16)wv[j]), acc);
                acc += __shfl_xor(acc, 1);
                acc += __shfl_xor(acc, 2);
                acc += __shfl_xor(acc, 4);
                acc += __shfl_xor(acc, 8);
                if (kc == 0) gp[col] = acc;
            }
        }
        __syncthreads();
        // B: LSTM cell
        if (tid < 128) {
            float gi = g0 + gp[tid];
            float gf = g1 + gp[128 + tid];
            float go = g2 + gp[256 + tid];
            float gg = g3 + gp[384 + tid];
            float c_new = sigm(gf) * cst[s][tid] + sigm(gi) * tanh_fast(gg);
            cst[s][tid] = c_new;
            hnew[tid] = sigm(go) * tanh_fast(c_new);
        }
        __syncthreads();
        // C: hv[h] = h_new . V_h[:,h] (L2-hot)
        {
            int h = tid & 127, jc = tid >> 7;
            float p = 0.f;
            if (isf32) {
                const float* vp = (const float*)V + (size_t)(HH + jc * 16) * HH + h;
                #pragma unroll
                for (int j = 0; j < 16; ++j)
                    p += hnew[jc * 16 + j] * vp[(size_t)j * HH];
            } else {
                const u16* vp = (const u16*)V + (size_t)(HH + jc * 16) * HH + h;
                #pragma unroll
                for (int j = 0; j < 16; ++j)
                    p += hnew[jc * 16 + j] * bf2f(vp[(size_t)j * HH]);
            }
            dred[jc][h] = p;
        }
        __syncthreads();
        if (tid < 128) {
            float v = 0.f;
            #pragma unroll
            for (int s2 = 0; s2 < 8; ++s2) v += dred[s2][tid];
            hvC[tid] = v * C2T;
        }
        __syncthreads();
        // D: partial tanh sums over own 128-e slice (bf16 encT from L2)
        {
            int e = tid & 127, hc = tid >> 7;
            const u16* ep = encTg16 + (size_t)(b * 128 + hc * 16) * EE + k * 128 + e;
            float sumr = 0.f;
            #pragma unroll
            for (int j = 0; j < 16; ++j) {
                float a = bf2f(ep[(size_t)j * EE]) + hvC[hc * 16 + j];
                sumr += __builtin_amdgcn_rcpf(__builtin_amdgcn_exp2f(a) + 1.f);
            }
            dred[hc][e] = sumr;
        }
        __syncthreads();
        // E: local scores + local softmax stats
        float s_e = 0.f;
        if (tid < 128) {
            float sr = 0.f;
            #pragma unroll
            for (int s2 = 0; s2 < 8; ++s2) sr += dred[s2][tid];
            s_e = 128.f - 2.f * sr;
            float m = s_e;
            #pragma unroll
            for (int off = 32; off; off >>= 1) m = fmaxf(m, __shfl_xor(m, off));
            if ((tid & 63) == 0) redw[tid >> 6] = m;
        }
        __syncthreads();
        if (tid < 128) {
            float mloc = fmaxf(redw[0], redw[1]);
            float p_reg = __builtin_amdgcn_exp2f((s_e - mloc) * LOG2E);
            sc[s][tid] = p_reg;
            float ss = p_reg;
            #pragma unroll
            for (int off = 32; off; off >>= 1) ss += __shfl_xor(ss, off);
            if ((tid & 63) == 0) redw2[tid >> 6] = ss;
            if (tid == 0) m_sv[s] = mloc;
        }
        __syncthreads();
        if (tid == 0) s_sv[s] = redw2[0] + redw2[1];
        // F: partial unnormalized context over own e-slice (enc from L2)
        {
            int h = tid & 127, ec = tid >> 7;
            float p = 0.f;
            if (isf32) {
                const float* eb = (const float*)enc_out +
                    ((size_t)b * EE + k * 128 + ec * 16) * HH + h;
                #pragma unroll
                for (int j = 0; j < 16; ++j)
                    p += sc[s][ec * 16 + j] * eb[(size_t)j * HH];
            } else {
                const u16* eb = (const u16*)enc_out +
                    ((size_t)b * EE + k * 128 + ec * 16) * HH + h;
                #pragma unroll
                for (int j = 0; j < 16; ++j)
                    p += sc[s][ec * 16 + j] * bf2f(eb[(size_t)j * HH]);
            }
            dred[ec][h] = p;
        }
        __syncthreads();
        // reduce U and publish (tag-packed relaxed u64 atomics)
        float Uv = 0.f;
        if (tid < 128) {
            #pragma unroll
            for (int s2 = 0; s2 < 8; ++s2) Uv += dred[s2][tid];
        }
        {
            u64* pp = payu + ((size_t)(b * 8 + k) * 2 + (t & 1)) * 130;
            if (tid < 130) {
                float val = (tid < 128) ? Uv : ((tid == 128) ? m_sv[s] : s_sv[s]);
                union { float f; unsigned int u; } cv; cv.f = val;
                u64 w = ((u64)want << 32) | (u64)cv.u;
                __hip_atomic_store(&pp[tid], w, __ATOMIC_RELAXED, __HIP_MEMORY_SCOPE_AGENT);
                selfp[s][tid] = val;
            }
        }
        // no trailing barrier: next code region's first barrier orders reuse
    };

    // -------- poll partners + combine (canonical order, replicated) -------
    auto pollcombine = [&](int s, int b, int t) {
        const unsigned int want = (unsigned int)(t + 1);
        if (tid < 130) exch[k][tid] = selfp[s][tid];
        if (tid < 910) {
            int qq = tid / 130;
            int q = qq + (qq >= k ? 1 : 0);
            int idx = tid - qq * 130;
            const u64* qp = payu + ((size_t)(b * 8 + q) * 2 + (t & 1)) * 130 + idx;
            u64 w = __hip_atomic_load(qp, __ATOMIC_RELAXED, __HIP_MEMORY_SCOPE_AGENT);
            int cnt = 0;
            while ((unsigned int)(w >> 32) != want) {
                __builtin_amdgcn_s_sleep(1);
                w = __hip_atomic_load(qp, __ATOMIC_RELAXED, __HIP_MEMORY_SCOPE_AGENT);
                if (++cnt > (1 << 20)) break;   // fail visibly, never hang
            }
            union { unsigned int u; float f; } cv; cv.u = (unsigned int)(w & 0xFFFFFFFFu);
            exch[q][idx] = cv.f;
        }
        __syncthreads();
        if (tid < 128) {
            float M = exch[0][128];
            #pragma unroll
            for (int q = 1; q < 8; ++q) M = fmaxf(M, exch[q][128]);
            float St = 0.f, ch = 0.f;
            #pragma unroll
            for (int q = 0; q < 8; ++q) {
                float w = __builtin_amdgcn_exp2f((exch[q][128] - M) * LOG2E);
                St += w * exch[q][129];
                ch += w * exch[q][tid];
            }
            float rS = __builtin_amdgcn_rcpf(St);
            float ctx = ch * rS;
            harr[s][tid] = ctx;
            float al = sc[s][tid] * __builtin_amdgcn_exp2f((m_sv[s] - M) * LOG2E) * rS;
            stout(out, OFF_A + (size_t)(b * LL + t) * EE + k * 128 + tid, al, isf32);
            if (k == 0) {
                hs_bf[(size_t)(b * LL + t) * HH + tid] = f2bf(ctx);
                if (t == LL - 1) {
                    stout(out, OFF_H + (size_t)b * HH + tid, ctx, isf32);
                    stout(out, OFF_C + (size_t)b * HH + tid, cst[s][tid], isf32);
                }
            }
        }
        __syncthreads();
    };

    // -------- software-pipelined dual-batch schedule ----------------------
    phases(0, b0, 0);
    for (int t = 0; t < LL; ++t) {
        phases(1, b1, t);            // batch-1 compute hides batch-0 RT
        pollcombine(0, b0, t);
        if (t < LL - 1)
            phases(0, b0, t + 1);    // batch-0 compute hides batch-1 RT
        pollcombine(1, b1, t);
    }
}

// ---- logits = hs @ w_soft : MFMA bf16 ------------------------------------
__global__ __launch_bounds__(256) void logits_gemm(
    const u16* __restrict__ hs, const u16* __restrict__ wT,
    void* __restrict__ out, const int* __restrict__ flagp)
{
    int isf32 = !flagp[0];
    int n0 = blockIdx.x * 32;
    int m0 = (blockIdx.y * 4 + (threadIdx.x >> 6)) * 32;
    int lane = threadIdx.x & 63;
    int lr = lane & 15, lh = lane >> 4;
    f32x4 acc00 = {0.f, 0.f, 0.f, 0.f}, acc01 = acc00, acc10 = acc00, acc11 = acc00;
    const u16* a0p = hs + (size_t)(m0 + lr) * HH + lh * 8;
    const u16* a1p = a0p + (size_t)16 * HH;
    const u16* b0p = wT + (size_t)(n0 + lr) * HH + lh * 8;
    const u16* b1p = b0p + (size_t)16 * HH;
    #pragma unroll
    for (int ks = 0; ks < 4; ++ks) {
        bf16x8 a0 = *(const bf16x8*)(a0p + ks * 32);
        bf16x8 a1 = *(const bf16x8*)(a1p + ks * 32);
        bf16x8 b0 = *(const bf16x8*)(b0p + ks * 32);
        bf16x8 b1 = *(const bf16x8*)(b1p + ks * 32);
        acc00 = __builtin_amdgcn_mfma_f32_16x16x32_bf16(a0, b0, acc00, 0, 0, 0);
        acc01 = __builtin_amdgcn_mfma_f32_16x16x32_bf16(a0, b1, acc01, 0, 0, 0);
        acc10 = __builtin_amdgcn_mfma_f32_16x16x32_bf16(a1, b0, acc10, 0, 0, 0);
        acc11 = __builtin_amdgcn_mfma_f32_16x16x32_bf16(a1, b1, acc11, 0, 0, 0);
    }
    size_t base0 = (size_t)(m0 + lh * 4) * VV + n0;
    size_t base1 = (size_t)(m0 + 16 + lh * 4) * VV + n0;
    #pragma unroll
    for (int r = 0; r < 4; ++r) {
        stout(out, base0 + (size_t)r * VV + lr,      acc00[r], isf32);
        stout(out, base0 + (size_t)r * VV + 16 + lr, acc01[r], isf32);
        stout(out, base1 + (size_t)r * VV + lr,      acc10[r], isf32);
        stout(out, base1 + (size_t)r * VV + 16 + lr, acc11[r], isf32);
    }
}

extern "C" void kernel_launch(void* const* d_in, const int* in_sizes, int n_in,
                              void* d_out, int out_size, void* d_ws, size_t ws_size,
                              hipStream_t stream)
{
    (void)in_sizes; (void)n_in; (void)out_size;
    if (ws_size < WS_NEED) return;

    const int* sent     = (const int*)d_in[0];
    const void* init_c  = d_in[1];
    const void* init_h  = d_in[2];
    const void* enc_out = d_in[3];
    const void* w_emb   = d_in[4];
    const void* w_lstm  = d_in[5];
    const void* w_soft  = d_in[6];
    const void* V       = d_in[7];

    char* ws = (char*)d_ws;
    u16*   encT  = (u16*)(ws + WS_ENCT);
    u16*   wrecT = (u16*)(ws + WS_WREC);
    u16*   hs    = (u16*)(ws + WS_HS);
    float* gx    = (float*)(ws + WS_GX);
    u64*   payu  = (u64*)(ws + WS_PAYU);
    u16*   wT    = (u16*)(ws + WS_WT);
    int*   dflag = (int*)(ws + WS_DFL);

    hipLaunchKernelGGL(resetdetect_kernel, dim3((PAYU_WORDS + 255) / 256), dim3(256), 0, stream,
                       payu, (const unsigned int*)w_emb, dflag);
    hipLaunchKernelGGL(prep_wrec, dim3(16, 4), dim3(1024), 0, stream, w_lstm, wrecT, dflag);
    hipLaunchKernelGGL(gatesx3_kernel, dim3(128), dim3(256), 0, stream,
                       sent, w_emb, w_lstm, gx, dflag);
    hipLaunchKernelGGL(encproj_kernel, dim3(16, BB), dim3(256), 0, stream, enc_out, V, encT, dflag);

    {
        const void* a0 = init_c; const void* a1 = init_h; const void* a2 = enc_out;
        const u16* a3 = wrecT; const void* a4 = V; const u16* a5 = encT;
        const float* a6 = gx; u16* a7 = hs; void* a8 = d_out;
        u64* a9 = payu; const int* a10 = dflag;
        void* args[] = {&a0, &a1, &a2, &a3, &a4, &a5, &a6, &a7, &a8, &a9, &a10};
        hipLaunchCooperativeKernel(scan_kernel, dim3(128), dim3(1024), args, 0, stream);
    }

    hipLaunchKernelGGL(transpose_wsoft, dim3(VV / 32, 4), dim3(1024), 0, stream, w_soft, wT, dflag);
    hipLaunchKernelGGL(logits_gemm, dim3(VV / 32, 16), dim3(256), 0, stream, hs, wT, d_out, dflag);
}

// Round 11
// 1003.506 us; speedup vs baseline: 2.2105x; 2.2105x over previous
//
#include <hip/hip_runtime.h>
#include <hip/hip_bf16.h>

#define BB 32
#define LL 64
#define EE 1024
#define HH 128
#define VV 32000

typedef unsigned short u16;
typedef unsigned long long u64;
typedef __attribute__((ext_vector_type(8))) short bf16x8;
typedef __attribute__((ext_vector_type(8))) unsigned short u16x8;
typedef __attribute__((ext_vector_type(4))) float f32x4;

#define LOG2E 1.4426950408889634f
#define C2T   2.8853900817779268f   // 2*log2(e)

// output element offsets (return order: logits, c_fin, h_fin, alphas)
#define OFF_C ((size_t)BB * LL * VV)
#define OFF_H (OFF_C + (size_t)BB * HH)
#define OFF_A (OFF_H + (size_t)BB * HH)

// ws byte offsets
#define WS_ENCT 0                    // 8,388,608 B u16 encT [b][e][h] C2T-prescaled
#define WS_HS   ((size_t)8388608)    // 524,288 B bf16
#define WS_GX   ((size_t)8912896)    // 4,194,304 B f32
#define WS_PAYU ((size_t)13107200)   // 532,480 B u64 [32][8][2][130]
#define WS_PAYG ((size_t)13639680)   // 262,144 B u64 [32][8][2][64]
#define WS_WT   ((size_t)13901824)   // 8,192,000 B u16 w_softT
#define WS_DFL  ((size_t)22093824)   // 4 B detect flag
#define WS_NEED ((size_t)22093828)

#define PAYU_WORDS (32 * 8 * 2 * 130)   // 66,560
#define PAYG_WORDS (32 * 8 * 2 * 64)    // 32,768
#define PAY_TOTAL  (PAYU_WORDS + PAYG_WORDS)

__device__ __forceinline__ float bf2f(u16 u) {
    union { unsigned int i; float f; } v; v.i = ((unsigned int)u) << 16; return v.f;
}
__device__ __forceinline__ u16 f2bf(float f) {
    union { float f; unsigned int i; } v; v.f = f;
    unsigned int x = v.i;
    return (u16)((x + 0x7FFFu + ((x >> 16) & 1u)) >> 16);
}
__device__ __forceinline__ float ldf(const void* p, size_t i, int f32) {
    if (f32) return ((const float*)p)[i];
    return bf2f(((const u16*)p)[i]);
}
__device__ __forceinline__ void stout(void* p, size_t i, float v, int f32) {
    if (f32) ((float*)p)[i] = v;
    else ((u16*)p)[i] = f2bf(v);
}
__device__ __forceinline__ float sigm(float x) {
    return __builtin_amdgcn_rcpf(1.f + __builtin_amdgcn_exp2f(-x * LOG2E));
}
__device__ __forceinline__ float tanh_fast(float x) {
    return 1.f - 2.f * __builtin_amdgcn_rcpf(__builtin_amdgcn_exp2f(x * C2T) + 1.f);
}

// ---- payload reset + dtype detection (merged, 1 launch) ------------------
__global__ __launch_bounds__(256) void resetdetect_kernel(
    u64* __restrict__ pay, const unsigned int* __restrict__ w, int* __restrict__ flag)
{
    int i = blockIdx.x * 256 + threadIdx.x;
    if (i < PAY_TOTAL)
        pay[i] = 0ull;
    if (i == 0) {
        int cnt = 0;
        for (int j = 0; j < 256; ++j) {
            float a = fabsf(bf2f((u16)(w[j] & 0xFFFFu)));
            if (a > 1e-4f && a < 0.5f) ++cnt;
        }
        *flag = (cnt > 128) ? 1 : 0;     // 1 => inputs are bf16
    }
}

// ---- gates_x = w_emb[sent] @ w_lstm[0:128,:] (gather fused) --------------
__global__ __launch_bounds__(256) void gatesx3_kernel(
    const int* __restrict__ sent, const void* __restrict__ w_emb,
    const void* __restrict__ w_lstm, float* __restrict__ gx,
    const int* __restrict__ flagp)
{
    int isf32 = !flagp[0];
    int row0 = blockIdx.x * 16;
    int tid = threadIdx.x;
    __shared__ float xr[16][128];
    for (int i = tid; i < 2048; i += 256) {
        int r = i >> 7, col = i & 127;
        int id = sent[row0 + r];
        xr[r][col] = ldf(w_emb, (size_t)id * HH + col, isf32);
    }
    __syncthreads();
    int c0 = tid, c1 = tid + 256;
    float a0[16], a1[16];
    #pragma unroll
    for (int r = 0; r < 16; ++r) { a0[r] = 0.f; a1[r] = 0.f; }
    for (int kk = 0; kk < 128; ++kk) {
        float w0, w1;
        if (isf32) {
            w0 = ((const float*)w_lstm)[(size_t)kk * 512 + c0];
            w1 = ((const float*)w_lstm)[(size_t)kk * 512 + c1];
        } else {
            w0 = bf2f(((const u16*)w_lstm)[(size_t)kk * 512 + c0]);
            w1 = bf2f(((const u16*)w_lstm)[(size_t)kk * 512 + c1]);
        }
        #pragma unroll
        for (int r = 0; r < 16; ++r) {
            a0[r] += xr[r][kk] * w0;
            a1[r] += xr[r][kk] * w1;
        }
    }
    #pragma unroll
    for (int r = 0; r < 16; ++r) {
        gx[(size_t)(row0 + r) * 512 + c0] = a0[r];
        gx[(size_t)(row0 + r) * 512 + c1] = a1[r];
    }
}

// ---- w_softT = transpose(w_soft) : (VV, HH) bf16 -------------------------
__global__ __launch_bounds__(1024) void transpose_wsoft(
    const void* __restrict__ w_soft, u16* __restrict__ wT, const int* __restrict__ flagp)
{
    int isf32 = !flagp[0];
    __shared__ u16 tile[32][33];
    int n0 = blockIdx.x * 32;
    int k0 = blockIdx.y * 32;
    int tx = threadIdx.x & 31, ty = threadIdx.x >> 5;
    tile[ty][tx] = f2bf(ldf(w_soft, (size_t)(k0 + ty) * VV + n0 + tx, isf32));
    __syncthreads();
    wT[(size_t)(n0 + ty) * HH + k0 + tx] = tile[tx][ty];
}

// ---- encT[b][e][h] = bf16(C2T * (enc[b][e][:] . V_e[:][h])) --------------
__global__ __launch_bounds__(256) void encproj_kernel(
    const void* __restrict__ enc_out, const void* __restrict__ V,
    u16* __restrict__ encT, const int* __restrict__ flagp)
{
    int isf32 = !flagp[0];
    __shared__ float ve[HH][HH];
    int b = blockIdx.y;
    int e0 = blockIdx.x * 64;
    int tid = threadIdx.x;
    for (int i = tid; i < HH * HH; i += 256)
        ve[i >> 7][i & 127] = ldf(V, i, isf32);
    __syncthreads();
    int e = e0 + (tid & 63);
    int hb = (tid >> 6) * 32;
    size_t rowbase = ((size_t)b * EE + e) * HH;
    float acc[32];
    #pragma unroll
    for (int i = 0; i < 32; ++i) acc[i] = 0.f;
    for (int k0 = 0; k0 < HH; k0 += 16) {
        float ef[16];
        #pragma unroll
        for (int i = 0; i < 16; ++i) ef[i] = ldf(enc_out, rowbase + k0 + i, isf32);
        #pragma unroll
        for (int hh = 0; hh < 32; ++hh) {
            float a = acc[hh];
            #pragma unroll
            for (int kk = 0; kk < 16; ++kk)
                a += ef[kk] * ve[k0 + kk][hb + hh];
            acc[hh] = a;
        }
    }
    u16* outp = encT + ((size_t)b * EE + e) * HH;   // [b][e][h]
    #pragma unroll
    for (int hh = 0; hh < 32; ++hh)
        outp[hb + hh] = f2bf(acc[hh] * C2T);
}

// ---- cooperative scan: 8 blocks per batch; 7 barrier-stages per step -----
// Wave-local shuffle reductions replace LDS-roundtrip reductions (R8 had 11
// barrier stages; this has 7). Split-A + gate exchange + U exchange, both
// relaxed tag-packed u64 atomics (proven R8 protocol).
__global__ __launch_bounds__(1024) void scan_kernel(
    const void* __restrict__ init_c, const void* __restrict__ init_h,
    const void* __restrict__ enc_out, const void* __restrict__ w_lstm,
    const void* __restrict__ V, const u16* __restrict__ encTg16,
    const float* __restrict__ gx, u16* __restrict__ hs_bf,
    void* __restrict__ out, u64* __restrict__ payu, u64* __restrict__ payg,
    const int* __restrict__ flagp)
{
    const int isf32 = !flagp[0];
    const int bid = blockIdx.x;
    const int b = bid & 31, k = bid >> 5;      // 8 partners per batch
    const int tid = threadIdx.x;
    const int w = tid >> 6;                    // wave 0..15
    const int l = tid & 63;                    // lane

    __shared__ u16   wrec16[64 * 128];         // 16KB bf16 [colLocal][k]
    __shared__ u16   encTl[128][136];          // 34.8KB bf16 [e][h] padded
    __shared__ float encF[128][132];           // 67.6KB f32 [e][h] padded
    __shared__ float gall[512];
    __shared__ float harr[128], cst[128], hnew[128], hvC[128];
    __shared__ float sc[128];
    __shared__ float pairs[16][2];
    __shared__ float exch[8][132];

    // ---- one-time staging ----
    for (int i = tid; i < 128 * 128; i += 1024) {       // encT slice [e][h]
        int e = i >> 7, h = i & 127;
        encTl[e][h] = encTg16[((size_t)b * EE + k * 128 + e) * HH + h];
    }
    for (int i = tid; i < 128 * 128; i += 1024) {       // enc slice f32 [e][h]
        int e = i >> 7, h = i & 127;
        encF[e][h] = ldf(enc_out, ((size_t)b * EE + k * 128 + e) * HH + h, isf32);
    }
    for (int i = tid; i < 64 * 128; i += 1024) {        // w_rec col slice bf16
        int c = i >> 7, kk = i & 127;
        wrec16[c * 128 + kk] = f2bf(ldf(w_lstm, (size_t)(HH + kk) * 512 + k * 64 + c, isf32));
    }
    if (tid < 128) {
        cst[tid]  = ldf(init_c, (size_t)b * HH + tid, isf32);
        harr[tid] = ldf(init_h, (size_t)b * HH + tid, isf32);
    }
    __syncthreads();

    u64* mypu = payu + (size_t)(b * 8 + k) * 2 * 130;
    u64* mypg = payg + (size_t)(b * 8 + k) * 2 * 64;

    for (int t = 0; t < LL; ++t) {
        const unsigned int want = (unsigned int)(t + 1);
        // prefetch gx words for B
        float g0 = 0.f, g1 = 0.f, g2 = 0.f, g3 = 0.f;
        if (tid < 128) {
            const float* gxr = gx + (size_t)(b * LL + t) * 512;
            g0 = gxr[tid]; g1 = gxr[128 + tid]; g2 = gxr[256 + tid]; g3 = gxr[384 + tid];
        }
        // A: this block's 64 gate cols (16 lanes/col) + publish + poll gates
        {
            int colL = tid >> 4, kc = tid & 15;
            const bf16x8 wv = *(const bf16x8*)&wrec16[colL * 128 + kc * 8];
            float acc = 0.f;
            #pragma unroll
            for (int j = 0; j < 8; ++j)
                acc = __builtin_fmaf(harr[kc * 8 + j], bf2f((u16)wv[j]), acc);
            acc += __shfl_xor(acc, 1);
            acc += __shfl_xor(acc, 2);
            acc += __shfl_xor(acc, 4);
            acc += __shfl_xor(acc, 8);
            if (kc == 0) {
                gall[(k << 6) + colL] = acc;
                union { float f; unsigned int u; } cv; cv.f = acc;
                u64 wd = ((u64)want << 32) | (u64)cv.u;
                __hip_atomic_store(&mypg[(size_t)(t & 1) * 64 + colL], wd,
                                   __ATOMIC_RELAXED, __HIP_MEMORY_SCOPE_AGENT);
            }
        }
        if (tid < 448) {
            int qq = tid >> 6;
            int q = qq + (qq >= k ? 1 : 0);
            int idx = tid & 63;
            const u64* qp = payg + ((size_t)(b * 8 + q) * 2 + (t & 1)) * 64 + idx;
            u64 wd = __hip_atomic_load(qp, __ATOMIC_RELAXED, __HIP_MEMORY_SCOPE_AGENT);
            int cnt = 0;
            while ((unsigned int)(wd >> 32) != want) {
                __builtin_amdgcn_s_sleep(1);
                wd = __hip_atomic_load(qp, __ATOMIC_RELAXED, __HIP_MEMORY_SCOPE_AGENT);
                if (++cnt > (1 << 20)) break;   // fail visibly, never hang
            }
            union { unsigned int u; float f; } cv; cv.u = (unsigned int)(wd & 0xFFFFFFFFu);
            gall[q * 64 + idx] = cv.f;
        }
        __syncthreads();                                   // bar1
        // B: LSTM cell (gall identical across replicas)
        if (tid < 128) {
            float gi = g0 + gall[tid];
            float gf = g1 + gall[128 + tid];
            float go = g2 + gall[256 + tid];
            float gg = g3 + gall[384 + tid];
            float c_new = sigm(gf) * cst[tid] + sigm(gi) * tanh_fast(gg);
            cst[tid] = c_new;
            hnew[tid] = sigm(go) * tanh_fast(c_new);
        }
        __syncthreads();                                   // bar2
        // C: wave-local hv[h]: h = 8w + (l>>3), 8 lanes sum 16 j-terms each
        {
            int r = l >> 3, c = l & 7;
            int h = 8 * w + r;
            float p = 0.f;
            if (isf32) {
                const float* vp = (const float*)V + (size_t)(HH + 16 * c) * HH + h;
                #pragma unroll
                for (int j = 0; j < 16; ++j)
                    p += hnew[16 * c + j] * vp[(size_t)j * HH];
            } else {
                const u16* vp = (const u16*)V + (size_t)(HH + 16 * c) * HH + h;
                #pragma unroll
                for (int j = 0; j < 16; ++j)
                    p += hnew[16 * c + j] * bf2f(vp[(size_t)j * HH]);
            }
            p += __shfl_xor(p, 1);
            p += __shfl_xor(p, 2);
            p += __shfl_xor(p, 4);
            if (c == 0) hvC[h] = p * C2T;
        }
        __syncthreads();                                   // bar3
        // D+E fused: e = 8w + (l>>3); 8 lanes (c) sum 16 h-terms each
        float s_e, m_loc, S_loc;
        {
            int r = l >> 3, c = l & 7;
            int e = 8 * w + r;
            const u16* ep = &encTl[e][16 * c];
            bf16x8 v0 = *(const bf16x8*)ep;
            bf16x8 v1 = *(const bf16x8*)(ep + 8);
            float sumr = 0.f;
            #pragma unroll
            for (int j = 0; j < 8; ++j) {
                float a = bf2f((u16)v0[j]) + hvC[16 * c + j];
                sumr += __builtin_amdgcn_rcpf(__builtin_amdgcn_exp2f(a) + 1.f);
            }
            #pragma unroll
            for (int j = 0; j < 8; ++j) {
                float a = bf2f((u16)v1[j]) + hvC[16 * c + 8 + j];
                sumr += __builtin_amdgcn_rcpf(__builtin_amdgcn_exp2f(a) + 1.f);
            }
            sumr += __shfl_xor(sumr, 1);
            sumr += __shfl_xor(sumr, 2);
            sumr += __shfl_xor(sumr, 4);
            s_e = 128.f - 2.f * sumr;                      // all lanes: score of own e
            float m = s_e;
            m = fmaxf(m, __shfl_xor(m, 8));
            m = fmaxf(m, __shfl_xor(m, 16));
            m = fmaxf(m, __shfl_xor(m, 32));               // wave max over its 8 e
            float pw = __builtin_amdgcn_exp2f((s_e - m) * LOG2E);
            float Sw = pw;
            Sw += __shfl_xor(Sw, 8);
            Sw += __shfl_xor(Sw, 16);
            Sw += __shfl_xor(Sw, 32);                      // wave sum (one lane per e)
            if (l == 0) { pairs[w][0] = m; pairs[w][1] = Sw; }
        }
        __syncthreads();                                   // bar4
        // merge wave stats (all threads, canonical order) + write sc[e]
        {
            m_loc = pairs[0][0];
            #pragma unroll
            for (int q = 1; q < 16; ++q) m_loc = fmaxf(m_loc, pairs[q][0]);
            S_loc = 0.f;
            #pragma unroll
            for (int q = 0; q < 16; ++q)
                S_loc += pairs[q][1] * __builtin_amdgcn_exp2f((pairs[q][0] - m_loc) * LOG2E);
            int r = l >> 3, c = l & 7;
            float p_e = __builtin_amdgcn_exp2f((s_e - m_loc) * LOG2E);
            if (c == 0) sc[8 * w + r] = p_e;
        }
        __syncthreads();                                   // bar5
        // F: wave-local U[h]: h = 8w + (l>>3); lanes (c) sum e = 8j + c
        {
            int r = l >> 3, c = l & 7;
            int h = 8 * w + r;
            float U = 0.f;
            #pragma unroll
            for (int j = 0; j < 16; ++j) {
                int e = 8 * j + c;
                U = __builtin_fmaf(sc[e], encF[e][h], U);
            }
            U += __shfl_xor(U, 1);
            U += __shfl_xor(U, 2);
            U += __shfl_xor(U, 4);                         // full U[h] at all 8 lanes
            u64* pp = mypu + (size_t)(t & 1) * 130;
            if (c == 0) {
                union { float f; unsigned int u; } cv; cv.f = U;
                u64 wd = ((u64)want << 32) | (u64)cv.u;
                __hip_atomic_store(&pp[h], wd, __ATOMIC_RELAXED, __HIP_MEMORY_SCOPE_AGENT);
                exch[k][h] = U;
            }
            if (tid == 128) {
                union { float f; unsigned int u; } cv; cv.f = m_loc;
                u64 wd = ((u64)want << 32) | (u64)cv.u;
                __hip_atomic_store(&pp[128], wd, __ATOMIC_RELAXED, __HIP_MEMORY_SCOPE_AGENT);
                exch[k][128] = m_loc;
            }
            if (tid == 129) {
                union { float f; unsigned int u; } cv; cv.f = S_loc;
                u64 wd = ((u64)want << 32) | (u64)cv.u;
                __hip_atomic_store(&pp[129], wd, __ATOMIC_RELAXED, __HIP_MEMORY_SCOPE_AGENT);
                exch[k][129] = S_loc;
            }
        }
        // poll partners' U payloads (910 threads)
        if (tid < 910) {
            int qq = tid / 130;
            int q = qq + (qq >= k ? 1 : 0);
            int idx = tid - qq * 130;
            const u64* qp = payu + ((size_t)(b * 8 + q) * 2 + (t & 1)) * 130 + idx;
            u64 wd = __hip_atomic_load(qp, __ATOMIC_RELAXED, __HIP_MEMORY_SCOPE_AGENT);
            int cnt = 0;
            while ((unsigned int)(wd >> 32) != want) {
                __builtin_amdgcn_s_sleep(1);
                wd = __hip_atomic_load(qp, __ATOMIC_RELAXED, __HIP_MEMORY_SCOPE_AGENT);
                if (++cnt > (1 << 20)) break;   // fail visibly, never hang
            }
            union { unsigned int u; float f; } cv; cv.u = (unsigned int)(wd & 0xFFFFFFFFu);
            exch[q][idx] = cv.f;
        }
        __syncthreads();                                   // bar6
        // combine in canonical order -> bit-identical context in all replicas
        if (tid < 128) {
            float M = exch[0][128];
            #pragma unroll
            for (int q = 1; q < 8; ++q) M = fmaxf(M, exch[q][128]);
            float St = 0.f, ch = 0.f;
            #pragma unroll
            for (int q = 0; q < 8; ++q) {
                float wq = __builtin_amdgcn_exp2f((exch[q][128] - M) * LOG2E);
                St += wq * exch[q][129];
                ch += wq * exch[q][tid];
            }
            float rS = __builtin_amdgcn_rcpf(St);
            float ctx = ch * rS;
            harr[tid] = ctx;
            float al = sc[tid] * __builtin_amdgcn_exp2f((m_loc - M) * LOG2E) * rS;
            stout(out, OFF_A + (size_t)(b * LL + t) * EE + k * 128 + tid, al, isf32);
            if (k == 0) {
                hs_bf[(size_t)(b * LL + t) * HH + tid] = f2bf(ctx);
                if (t == LL - 1) {
                    stout(out, OFF_H + (size_t)b * HH + tid, ctx, isf32);
                    stout(out, OFF_C + (size_t)b * HH + tid, cst[tid], isf32);
                }
            }
        }
        __syncthreads();                                   // bar7
    }
}

// ---- logits = hs @ w_soft : MFMA bf16 ------------------------------------
__global__ __launch_bounds__(256) void logits_gemm(
    const u16* __restrict__ hs, const u16* __restrict__ wT,
    void* __restrict__ out, const int* __restrict__ flagp)
{
    int isf32 = !flagp[0];
    int n0 = blockIdx.x * 32;
    int m0 = (blockIdx.y * 4 + (threadIdx.x >> 6)) * 32;
    int lane = threadIdx.x & 63;
    int lr = lane & 15, lh = lane >> 4;
    f32x4 acc00 = {0.f, 0.f, 0.f, 0.f}, acc01 = acc00, acc10 = acc00, acc11 = acc00;
    const u16* a0p = hs + (size_t)(m0 + lr) * HH + lh * 8;
    const u16* a1p = a0p + (size_t)16 * HH;
    const u16* b0p = wT + (size_t)(n0 + lr) * HH + lh * 8;
    const u16* b1p = b0p + (size_t)16 * HH;
    #pragma unroll
    for (int ks = 0; ks < 4; ++ks) {
        bf16x8 a0 = *(const bf16x8*)(a0p + ks * 32);
        bf16x8 a1 = *(const bf16x8*)(a1p + ks * 32);
        bf16x8 b0 = *(const bf16x8*)(b0p + ks * 32);
        bf16x8 b1 = *(const bf16x8*)(b1p + ks * 32);
        acc00 = __builtin_amdgcn_mfma_f32_16x16x32_bf16(a0, b0, acc00, 0, 0, 0);
        acc01 = __builtin_amdgcn_mfma_f32_16x16x32_bf16(a0, b1, acc01, 0, 0, 0);
        acc10 = __builtin_amdgcn_mfma_f32_16x16x32_bf16(a1, b0, acc10, 0, 0, 0);
        acc11 = __builtin_amdgcn_mfma_f32_16x16x32_bf16(a1, b1, acc11, 0, 0, 0);
    }
    size_t base0 = (size_t)(m0 + lh * 4) * VV + n0;
    size_t base1 = (size_t)(m0 + 16 + lh * 4) * VV + n0;
    #pragma unroll
    for (int r = 0; r < 4; ++r) {
        stout(out, base0 + (size_t)r * VV + lr,      acc00[r], isf32);
        stout(out, base0 + (size_t)r * VV + 16 + lr, acc01[r], isf32);
        stout(out, base1 + (size_t)r * VV + lr,      acc10[r], isf32);
        stout(out, base1 + (size_t)r * VV + 16 + lr, acc11[r], isf32);
    }
}

extern "C" void kernel_launch(void* const* d_in, const int* in_sizes, int n_in,
                              void* d_out, int out_size, void* d_ws, size_t ws_size,
                              hipStream_t stream)
{
    (void)in_sizes; (void)n_in; (void)out_size;
    if (ws_size < WS_NEED) return;

    const int* sent     = (const int*)d_in[0];
    const void* init_c  = d_in[1];
    const void* init_h  = d_in[2];
    const void* enc_out = d_in[3];
    const void* w_emb   = d_in[4];
    const void* w_lstm  = d_in[5];
    const void* w_soft  = d_in[6];
    const void* V       = d_in[7];

    char* ws = (char*)d_ws;
    u16*   encT  = (u16*)(ws + WS_ENCT);
    u16*   hs    = (u16*)(ws + WS_HS);
    float* gx    = (float*)(ws + WS_GX);
    u64*   payu  = (u64*)(ws + WS_PAYU);
    u64*   payg  = (u64*)(ws + WS_PAYG);
    u16*   wT    = (u16*)(ws + WS_WT);
    int*   dflag = (int*)(ws + WS_DFL);

    hipLaunchKernelGGL(resetdetect_kernel, dim3((PAY_TOTAL + 255) / 256), dim3(256), 0, stream,
                       payu, (const unsigned int*)w_emb, dflag);
    hipLaunchKernelGGL(gatesx3_kernel, dim3(128), dim3(256), 0, stream,
                       sent, w_emb, w_lstm, gx, dflag);
    hipLaunchKernelGGL(encproj_kernel, dim3(16, BB), dim3(256), 0, stream, enc_out, V, encT, dflag);

    {
        const void* a0 = init_c; const void* a1 = init_h; const void* a2 = enc_out;
        const void* a3 = w_lstm; const void* a4 = V; const u16* a5 = encT;
        const float* a6 = gx; u16* a7 = hs; void* a8 = d_out;
        u64* a9 = payu; u64* a10 = payg; const int* a11 = dflag;
        void* args[] = {&a0, &a1, &a2, &a3, &a4, &a5, &a6, &a7, &a8, &a9, &a10, &a11};
        hipLaunchCooperativeKernel(scan_kernel, dim3(256), dim3(1024), args, 0, stream);
    }

    hipLaunchKernelGGL(transpose_wsoft, dim3(VV / 32, 4), dim3(1024), 0, stream, w_soft, wT, dflag);
    hipLaunchKernelGGL(logits_gemm, dim3(VV / 32, 16), dim3(256), 0, stream, hs, wT, d_out, dflag);
}

// Round 12
// 879.910 us; speedup vs baseline: 2.5210x; 1.1405x over previous
//
#include <hip/hip_runtime.h>
#include <hip/hip_bf16.h>

#define BB 32
#define LL 64
#define EE 1024
#define HH 128
#define VV 32000

typedef unsigned short u16;
typedef unsigned long long u64;
typedef __attribute__((ext_vector_type(8))) short bf16x8;
typedef __attribute__((ext_vector_type(8))) unsigned short u16x8;
typedef __attribute__((ext_vector_type(4))) float f32x4;

#define LOG2E 1.4426950408889634f
#define C2T   2.8853900817779268f   // 2*log2(e)

// output element offsets (return order: logits, c_fin, h_fin, alphas)
#define OFF_C ((size_t)BB * LL * VV)
#define OFF_H (OFF_C + (size_t)BB * HH)
#define OFF_A (OFF_H + (size_t)BB * HH)

// ws byte offsets
#define WS_ENCT 0                    // 8,388,608 B u16 encT [b][h][e] C2T-prescaled
#define WS_HS   ((size_t)8388608)    // 524,288 B bf16
#define WS_GX   ((size_t)8912896)    // 4,194,304 B f32
#define WS_PAYU ((size_t)13107200)   // 532,480 B u64 [32][8][2][130]
#define WS_PAYG ((size_t)13639680)   // 262,144 B u64 [32][8][2][64]  (contiguous after PAYU)
#define WS_WT   ((size_t)13901824)   // 8,192,000 B u16 w_softT
#define WS_DFL  ((size_t)22093824)   // 4 B detect flag
#define WS_NEED ((size_t)22093828)

#define PAYU_WORDS (32 * 8 * 2 * 130)   // 66,560
#define PAYG_WORDS (32 * 8 * 2 * 64)    // 32,768
#define PAY_TOTAL  (PAYU_WORDS + PAYG_WORDS)   // 99,328

// mega-prep role ranges (256 threads per block)
#define RESET_BLKS ((PAY_TOTAL + 255) / 256)   // 388
#define GX_BLKS    128
#define ENC_BLKS   (16 * BB)                   // 512
#define TW_BLKS    ((VV / 32) * 4)             // 4000
#define PREP_BLKS  (RESET_BLKS + GX_BLKS + ENC_BLKS + TW_BLKS)

__device__ __forceinline__ float bf2f(u16 u) {
    union { unsigned int i; float f; } v; v.i = ((unsigned int)u) << 16; return v.f;
}
__device__ __forceinline__ u16 f2bf(float f) {
    union { float f; unsigned int i; } v; v.f = f;
    unsigned int x = v.i;
    return (u16)((x + 0x7FFFu + ((x >> 16) & 1u)) >> 16);
}
__device__ __forceinline__ float ldf(const void* p, size_t i, int f32) {
    if (f32) return ((const float*)p)[i];
    return bf2f(((const u16*)p)[i]);
}
__device__ __forceinline__ void stout(void* p, size_t i, float v, int f32) {
    if (f32) ((float*)p)[i] = v;
    else ((u16*)p)[i] = f2bf(v);
}
__device__ __forceinline__ float sigm(float x) {
    return __builtin_amdgcn_rcpf(1.f + __builtin_amdgcn_exp2f(-x * LOG2E));
}
__device__ __forceinline__ float tanh_fast(float x) {
    return 1.f - 2.f * __builtin_amdgcn_rcpf(__builtin_amdgcn_exp2f(x * C2T) + 1.f);
}

// ---- mega-prep: reset + detect + gatesx + encproj + w_soft transpose -----
__global__ __launch_bounds__(256) void megaprep_kernel(
    const int* __restrict__ sent, const void* __restrict__ w_emb,
    const void* __restrict__ w_lstm, const void* __restrict__ enc_out,
    const void* __restrict__ V, const void* __restrict__ w_soft,
    float* __restrict__ gx, u16* __restrict__ encT, u16* __restrict__ wT,
    u64* __restrict__ pay, int* __restrict__ flag)
{
    const int blk = blockIdx.x;
    const int tid = threadIdx.x;
    __shared__ float smem[16384];              // 64KB, aliased per role
    __shared__ int dcnt[4];

    if (blk < RESET_BLKS) {
        int i = blk * 256 + tid;
        if (i < PAY_TOTAL) pay[i] = 0ull;
        if (blk == 0) {
            // ballot-detect (write ws flag for the scan kernel)
            float a = fabsf(bf2f((u16)(((const unsigned int*)w_emb)[tid] & 0xFFFFu)));
            unsigned long long m = __ballot(a > 1e-4f && a < 0.5f);
            if ((tid & 63) == 0) dcnt[tid >> 6] = __popcll(m);
            __syncthreads();
            if (tid == 0)
                *flag = (dcnt[0] + dcnt[1] + dcnt[2] + dcnt[3] > 128) ? 1 : 0;
        }
        return;
    }
    // inline detect for all compute roles (no cross-block dependency)
    float da = fabsf(bf2f((u16)(((const unsigned int*)w_emb)[tid] & 0xFFFFu)));
    unsigned long long dm = __ballot(da > 1e-4f && da < 0.5f);
    if ((tid & 63) == 0) dcnt[tid >> 6] = __popcll(dm);
    __syncthreads();
    const int isf32 = !(dcnt[0] + dcnt[1] + dcnt[2] + dcnt[3] > 128);
    __syncthreads();

    if (blk < RESET_BLKS + GX_BLKS) {
        // gates_x = w_emb[sent] @ w_lstm[0:128,:]
        int row0 = (blk - RESET_BLKS) * 16;
        float (*xr)[128] = (float(*)[128])smem;
        for (int i = tid; i < 2048; i += 256) {
            int r = i >> 7, col = i & 127;
            int id = sent[row0 + r];
            xr[r][col] = ldf(w_emb, (size_t)id * HH + col, isf32);
        }
        __syncthreads();
        int c0 = tid, c1 = tid + 256;
        float a0[16], a1[16];
        #pragma unroll
        for (int r = 0; r < 16; ++r) { a0[r] = 0.f; a1[r] = 0.f; }
        for (int kk = 0; kk < 128; ++kk) {
            float w0, w1;
            if (isf32) {
                w0 = ((const float*)w_lstm)[(size_t)kk * 512 + c0];
                w1 = ((const float*)w_lstm)[(size_t)kk * 512 + c1];
            } else {
                w0 = bf2f(((const u16*)w_lstm)[(size_t)kk * 512 + c0]);
                w1 = bf2f(((const u16*)w_lstm)[(size_t)kk * 512 + c1]);
            }
            #pragma unroll
            for (int r = 0; r < 16; ++r) {
                a0[r] += xr[r][kk] * w0;
                a1[r] += xr[r][kk] * w1;
            }
        }
        #pragma unroll
        for (int r = 0; r < 16; ++r) {
            gx[(size_t)(row0 + r) * 512 + c0] = a0[r];
            gx[(size_t)(row0 + r) * 512 + c1] = a1[r];
        }
        return;
    }
    if (blk < RESET_BLKS + GX_BLKS + ENC_BLKS) {
        // encT[b][h][e] = bf16(C2T * enc[b][e][:] . V_e[:][h])
        int idx = blk - RESET_BLKS - GX_BLKS;
        int b = idx >> 4;
        int e0 = (idx & 15) * 64;
        float (*ve)[128] = (float(*)[128])smem;
        for (int i = tid; i < HH * HH; i += 256)
            ve[i >> 7][i & 127] = ldf(V, i, isf32);
        __syncthreads();
        int e = e0 + (tid & 63);
        int hb = (tid >> 6) * 32;
        size_t rowbase = ((size_t)b * EE + e) * HH;
        float acc[32];
        #pragma unroll
        for (int i = 0; i < 32; ++i) acc[i] = 0.f;
        for (int k0 = 0; k0 < HH; k0 += 16) {
            float ef[16];
            #pragma unroll
            for (int i = 0; i < 16; ++i) ef[i] = ldf(enc_out, rowbase + k0 + i, isf32);
            #pragma unroll
            for (int hh = 0; hh < 32; ++hh) {
                float a = acc[hh];
                #pragma unroll
                for (int kk = 0; kk < 16; ++kk)
                    a += ef[kk] * ve[k0 + kk][hb + hh];
                acc[hh] = a;
            }
        }
        u16* outp = encT + ((size_t)b * HH) * EE + e;   // [b][h][e]
        #pragma unroll
        for (int hh = 0; hh < 32; ++hh)
            outp[(size_t)(hh + hb) * EE] = f2bf(acc[hh] * C2T);
        return;
    }
    // w_softT = transpose(w_soft) : (VV, HH) bf16
    {
        int idx = blk - RESET_BLKS - GX_BLKS - ENC_BLKS;
        int n0 = (idx >> 2) * 32;
        int k0 = (idx & 3) * 32;
        u16 (*tile)[33] = (u16(*)[33])smem;
        int tx = tid & 31, ty0 = tid >> 5;     // 8 rows per iter
        #pragma unroll
        for (int i = 0; i < 4; ++i) {
            int ty = ty0 + i * 8;
            tile[ty][tx] = f2bf(ldf(w_soft, (size_t)(k0 + ty) * VV + n0 + tx, isf32));
        }
        __syncthreads();
        #pragma unroll
        for (int i = 0; i < 4; ++i) {
            int ty = ty0 + i * 8;
            wT[(size_t)(n0 + ty) * HH + k0 + tx] = tile[tx][ty];
        }
    }
}

// ---- cooperative scan: 8 blocks per batch, e-slice of 128 per block ------
// R8 structure (best verified: 531us) + V_h in LDS (bf16) + LDS-atomic
// reductions for hvC/U (removes 1 barrier + 2 LDS roundtrips).
// Exchange: relaxed tag-packed u64 atomics (proven protocol).
__global__ __launch_bounds__(1024) void scan_kernel(
    const void* __restrict__ init_c, const void* __restrict__ init_h,
    const void* __restrict__ enc_out, const void* __restrict__ w_lstm,
    const void* __restrict__ V, const u16* __restrict__ encTg16,
    const float* __restrict__ gx, u16* __restrict__ hs_bf,
    void* __restrict__ out, u64* __restrict__ payu, u64* __restrict__ payg,
    const int* __restrict__ flagp)
{
    const int isf32 = !flagp[0];
    const int bid = blockIdx.x;
    const int b = bid & 31, k = bid >> 5;      // 8 partners per batch, same XCD
    const int tid = threadIdx.x;

    __shared__ u16   encTl16[128][128];        // 32KB bf16 [h][e] C2T-prescaled
    __shared__ float encF[128][128];           // 64KB f32 [e][h]
    __shared__ u16   wrec16[64 * 128];         // 16KB bf16 [colLocal][k]
    __shared__ u16   vhl[128][128];            // 32KB bf16 V_h [j][h]
    __shared__ float dred[8][128];             // scratch (D); aliased as gall (A/B)
    __shared__ float harr[128], cst[128], hnew[128], hvC[128], Ul[128];
    __shared__ float sc[128];
    __shared__ float exch[8][130];
    __shared__ float redw[2], redw2[2];
    __shared__ float m_s, s_s;
    float* gall = &dred[0][0];                 // 512 floats, time-disjoint with dred

    // ---- one-time staging ----
    for (int i = tid; i < 128 * 128; i += 1024) {       // encT slice bf16 [h][e]
        int h = i >> 7, e = i & 127;
        encTl16[h][e] = encTg16[(size_t)(b * 128 + h) * EE + k * 128 + e];
    }
    for (int i = tid; i < 128 * 128; i += 1024) {       // enc slice f32 [e][h]
        int e = i >> 7, hh = i & 127;
        encF[e][hh] = ldf(enc_out, ((size_t)b * EE + k * 128 + e) * HH + hh, isf32);
    }
    for (int i = tid; i < 128 * 128; i += 1024) {       // V_h bf16 [j][h]
        int j = i >> 7, h = i & 127;
        vhl[j][h] = f2bf(ldf(V, (size_t)(HH + j) * HH + h, isf32));
    }
    for (int i = tid; i < 64 * 128; i += 1024) {        // w_rec col slice bf16
        int c = i >> 7, kk = i & 127;
        wrec16[c * 128 + kk] = f2bf(ldf(w_lstm, (size_t)(HH + kk) * 512 + k * 64 + c, isf32));
    }
    if (tid < 128) {
        cst[tid]  = ldf(init_c, (size_t)b * HH + tid, isf32);
        harr[tid] = ldf(init_h, (size_t)b * HH + tid, isf32);
    }
    __syncthreads();

    u64* mypu = payu + (size_t)(b * 8 + k) * 2 * 130;
    u64* mypg = payg + (size_t)(b * 8 + k) * 2 * 64;

    for (int t = 0; t < LL; ++t) {
        const unsigned int want = (unsigned int)(t + 1);
        // prefetch gx words for B
        float g0 = 0.f, g1 = 0.f, g2 = 0.f, g3 = 0.f;
        if (tid < 128) {
            const float* gxr = gx + (size_t)(b * LL + t) * 512;
            g0 = gxr[tid]; g1 = gxr[128 + tid]; g2 = gxr[256 + tid]; g3 = gxr[384 + tid];
        }
        // A: this block's 64 gate cols (16 lanes/col) + publish + poll gates
        {
            int colL = tid >> 4, kc = tid & 15;
            const bf16x8 wv = *(const bf16x8*)&wrec16[colL * 128 + kc * 8];
            float acc = 0.f;
            #pragma unroll
            for (int j = 0; j < 8; ++j)
                acc = __builtin_fmaf(harr[kc * 8 + j], bf2f((u16)wv[j]), acc);
            acc += __shfl_xor(acc, 1);
            acc += __shfl_xor(acc, 2);
            acc += __shfl_xor(acc, 4);
            acc += __shfl_xor(acc, 8);
            if (kc == 0) {
                gall[(k << 6) + colL] = acc;
                union { float f; unsigned int u; } cv; cv.f = acc;
                u64 wd = ((u64)want << 32) | (u64)cv.u;
                __hip_atomic_store(&mypg[(size_t)(t & 1) * 64 + colL], wd,
                                   __ATOMIC_RELAXED, __HIP_MEMORY_SCOPE_AGENT);
            }
        }
        if (tid < 448) {
            int qq = tid >> 6;
            int q = qq + (qq >= k ? 1 : 0);
            int idx = tid & 63;
            const u64* qp = payg + ((size_t)(b * 8 + q) * 2 + (t & 1)) * 64 + idx;
            u64 wd = __hip_atomic_load(qp, __ATOMIC_RELAXED, __HIP_MEMORY_SCOPE_AGENT);
            int cnt = 0;
            while ((unsigned int)(wd >> 32) != want) {
                __builtin_amdgcn_s_sleep(1);
                wd = __hip_atomic_load(qp, __ATOMIC_RELAXED, __HIP_MEMORY_SCOPE_AGENT);
                if (++cnt > (1 << 20)) break;   // fail visibly, never hang
            }
            union { unsigned int u; float f; } cv; cv.u = (unsigned int)(wd & 0xFFFFFFFFu);
            gall[q * 64 + idx] = cv.f;
        }
        __syncthreads();                                   // bar1
        // B: LSTM cell (gall identical across replicas); zero hvC for C
        if (tid < 128) {
            float gi = g0 + gall[tid];
            float gf = g1 + gall[128 + tid];
            float go = g2 + gall[256 + tid];
            float gg = g3 + gall[384 + tid];
            float c_new = sigm(gf) * cst[tid] + sigm(gi) * tanh_fast(gg);
            cst[tid] = c_new;
            hnew[tid] = sigm(go) * tanh_fast(c_new);
        } else if (tid < 256) {
            hvC[tid - 128] = 0.f;
        }
        __syncthreads();                                   // bar2
        // C: hv[h] += h_new . V_h[:,h] via LDS atomics (bf16 V_h from LDS)
        {
            int h = tid & 127, jc = tid >> 7;
            float p = 0.f;
            #pragma unroll
            for (int j = 0; j < 16; ++j)
                p = __builtin_fmaf(hnew[jc * 16 + j], bf2f(vhl[jc * 16 + j][h]), p);
            atomicAdd(&hvC[h], p * C2T);
        }
        __syncthreads();                                   // bar3
        // D: partial tanh sums over own 128-e slice (bf16 encT, LDS)
        {
            int e = tid & 127, hc = tid >> 7;
            float sumr = 0.f;
            #pragma unroll
            for (int j = 0; j < 16; ++j) {
                int h = hc * 16 + j;
                float a = bf2f(encTl16[h][e]) + hvC[h];
                sumr += __builtin_amdgcn_rcpf(__builtin_amdgcn_exp2f(a) + 1.f);
            }
            dred[hc][e] = sumr;
        }
        __syncthreads();                                   // bar4
        // E1: local scores + wave max; zero Ul for F
        float s_e = 0.f, p_reg = 0.f;
        if (tid < 128) {
            float sr = 0.f;
            #pragma unroll
            for (int s = 0; s < 8; ++s) sr += dred[s][tid];
            s_e = 128.f - 2.f * sr;
            float m = s_e;
            #pragma unroll
            for (int off = 32; off; off >>= 1) m = fmaxf(m, __shfl_xor(m, off));
            if ((tid & 63) == 0) redw[tid >> 6] = m;
        } else if (tid < 256) {
            Ul[tid - 128] = 0.f;
        }
        __syncthreads();                                   // bar5
        // E2: local softmax stats
        if (tid < 128) {
            float mloc = fmaxf(redw[0], redw[1]);
            p_reg = __builtin_amdgcn_exp2f((s_e - mloc) * LOG2E);
            sc[tid] = p_reg;
            float s = p_reg;
            #pragma unroll
            for (int off = 32; off; off >>= 1) s += __shfl_xor(s, off);
            if ((tid & 63) == 0) redw2[tid >> 6] = s;
            if (tid == 0) m_s = mloc;
        }
        __syncthreads();                                   // bar6
        if (tid == 0) s_s = redw2[0] + redw2[1];
        // F: partial unnormalized context (f32 enc, LDS) via LDS atomics
        {
            int h = tid & 127, ec = tid >> 7;
            float p = 0.f;
            #pragma unroll
            for (int j = 0; j < 16; ++j)
                p = __builtin_fmaf(sc[ec * 16 + j], encF[ec * 16 + j][h], p);
            atomicAdd(&Ul[h], p);
        }
        __syncthreads();                                   // bar7
        // publish [U(128), m, S] with parity t&1 (tag-packed relaxed u64)
        {
            u64* pp = mypu + (size_t)(t & 1) * 130;
            if (tid < 130) {
                float val = (tid < 128) ? Ul[tid] : ((tid == 128) ? m_s : s_s);
                union { float f; unsigned int u; } cv; cv.f = val;
                u64 wd = ((u64)want << 32) | (u64)cv.u;
                __hip_atomic_store(&pp[tid], wd, __ATOMIC_RELAXED, __HIP_MEMORY_SCOPE_AGENT);
                exch[k][tid] = val;
            }
        }
        // poll partners' U payloads (910 threads, one word each)
        if (tid < 910) {
            int qq = tid / 130;
            int q = qq + (qq >= k ? 1 : 0);
            int idx = tid - qq * 130;
            const u64* qp = payu + ((size_t)(b * 8 + q) * 2 + (t & 1)) * 130 + idx;
            u64 wd = __hip_atomic_load(qp, __ATOMIC_RELAXED, __HIP_MEMORY_SCOPE_AGENT);
            int cnt = 0;
            while ((unsigned int)(wd >> 32) != want) {
                __builtin_amdgcn_s_sleep(1);
                wd = __hip_atomic_load(qp, __ATOMIC_RELAXED, __HIP_MEMORY_SCOPE_AGENT);
                if (++cnt > (1 << 20)) break;   // fail visibly, never hang
            }
            union { unsigned int u; float f; } cv; cv.u = (unsigned int)(wd & 0xFFFFFFFFu);
            exch[q][idx] = cv.f;
        }
        __syncthreads();                                   // bar8
        // combine in canonical order -> bit-identical context in all replicas
        if (tid < 128) {
            float M = exch[0][128];
            #pragma unroll
            for (int q = 1; q < 8; ++q) M = fmaxf(M, exch[q][128]);
            float St = 0.f, ch = 0.f;
            #pragma unroll
            for (int q = 0; q < 8; ++q) {
                float wq = __builtin_amdgcn_exp2f((exch[q][128] - M) * LOG2E);
                St += wq * exch[q][129];
                ch += wq * exch[q][tid];
            }
            float rS = __builtin_amdgcn_rcpf(St);
            float ctx = ch * rS;
            harr[tid] = ctx;
            float al = p_reg * __builtin_amdgcn_exp2f((m_s - M) * LOG2E) * rS;
            stout(out, OFF_A + (size_t)(b * LL + t) * EE + k * 128 + tid, al, isf32);
            if (k == 0) {
                hs_bf[(size_t)(b * LL + t) * HH + tid] = f2bf(ctx);
                if (t == LL - 1) {
                    stout(out, OFF_H + (size_t)b * HH + tid, ctx, isf32);
                    stout(out, OFF_C + (size_t)b * HH + tid, cst[tid], isf32);
                }
            }
        }
        __syncthreads();                                   // bar9
    }
}

// ---- logits = hs @ w_soft : MFMA bf16 ------------------------------------
__global__ __launch_bounds__(256) void logits_gemm(
    const u16* __restrict__ hs, const u16* __restrict__ wT,
    void* __restrict__ out, const int* __restrict__ flagp)
{
    int isf32 = !flagp[0];
    int n0 = blockIdx.x * 32;
    int m0 = (blockIdx.y * 4 + (threadIdx.x >> 6)) * 32;
    int lane = threadIdx.x & 63;
    int lr = lane & 15, lh = lane >> 4;
    f32x4 acc00 = {0.f, 0.f, 0.f, 0.f}, acc01 = acc00, acc10 = acc00, acc11 = acc00;
    const u16* a0p = hs + (size_t)(m0 + lr) * HH + lh * 8;
    const u16* a1p = a0p + (size_t)16 * HH;
    const u16* b0p = wT + (size_t)(n0 + lr) * HH + lh * 8;
    const u16* b1p = b0p + (size_t)16 * HH;
    #pragma unroll
    for (int ks = 0; ks < 4; ++ks) {
        bf16x8 a0 = *(const bf16x8*)(a0p + ks * 32);
        bf16x8 a1 = *(const bf16x8*)(a1p + ks * 32);
        bf16x8 b0 = *(const bf16x8*)(b0p + ks * 32);
        bf16x8 b1 = *(const bf16x8*)(b1p + ks * 32);
        acc00 = __builtin_amdgcn_mfma_f32_16x16x32_bf16(a0, b0, acc00, 0, 0, 0);
        acc01 = __builtin_amdgcn_mfma_f32_16x16x32_bf16(a0, b1, acc01, 0, 0, 0);
        acc10 = __builtin_amdgcn_mfma_f32_16x16x32_bf16(a1, b0, acc10, 0, 0, 0);
        acc11 = __builtin_amdgcn_mfma_f32_16x16x32_bf16(a1, b1, acc11, 0, 0, 0);
    }
    size_t base0 = (size_t)(m0 + lh * 4) * VV + n0;
    size_t base1 = (size_t)(m0 + 16 + lh * 4) * VV + n0;
    #pragma unroll
    for (int r = 0; r < 4; ++r) {
        stout(out, base0 + (size_t)r * VV + lr,      acc00[r], isf32);
        stout(out, base0 + (size_t)r * VV + 16 + lr, acc01[r], isf32);
        stout(out, base1 + (size_t)r * VV + lr,      acc10[r], isf32);
        stout(out, base1 + (size_t)r * VV + 16 + lr, acc11[r], isf32);
    }
}

extern "C" void kernel_launch(void* const* d_in, const int* in_sizes, int n_in,
                              void* d_out, int out_size, void* d_ws, size_t ws_size,
                              hipStream_t stream)
{
    (void)in_sizes; (void)n_in; (void)out_size;
    if (ws_size < WS_NEED) return;

    const int* sent     = (const int*)d_in[0];
    const void* init_c  = d_in[1];
    const void* init_h  = d_in[2];
    const void* enc_out = d_in[3];
    const void* w_emb   = d_in[4];
    const void* w_lstm  = d_in[5];
    const void* w_soft  = d_in[6];
    const void* V       = d_in[7];

    char* ws = (char*)d_ws;
    u16*   encT  = (u16*)(ws + WS_ENCT);
    u16*   hs    = (u16*)(ws + WS_HS);
    float* gx    = (float*)(ws + WS_GX);
    u64*   payu  = (u64*)(ws + WS_PAYU);
    u64*   payg  = (u64*)(ws + WS_PAYG);
    u16*   wT    = (u16*)(ws + WS_WT);
    int*   dflag = (int*)(ws + WS_DFL);

    hipLaunchKernelGGL(megaprep_kernel, dim3(PREP_BLKS), dim3(256), 0, stream,
                       sent, w_emb, w_lstm, enc_out, V, w_soft,
                       gx, encT, wT, payu, dflag);

    {
        const void* a0 = init_c; const void* a1 = init_h; const void* a2 = enc_out;
        const void* a3 = w_lstm; const void* a4 = V; const u16* a5 = encT;
        const float* a6 = gx; u16* a7 = hs; void* a8 = d_out;
        u64* a9 = payu; u64* a10 = payg; const int* a11 = dflag;
        void* args[] = {&a0, &a1, &a2, &a3, &a4, &a5, &a6, &a7, &a8, &a9, &a10, &a11};
        hipLaunchCooperativeKernel(scan_kernel, dim3(256), dim3(1024), args, 0, stream);
    }

    hipLaunchKernelGGL(logits_gemm, dim3(VV / 32, 16), dim3(256), 0, stream, hs, wT, d_out, dflag);
}

// Round 13
// 750.979 us; speedup vs baseline: 2.9538x; 1.1717x over previous
//
#include <hip/hip_runtime.h>
#include <hip/hip_bf16.h>

#define BB 32
#define LL 64
#define EE 1024
#define HH 128
#define VV 32000

typedef unsigned short u16;
typedef unsigned long long u64;
typedef __attribute__((ext_vector_type(8))) short bf16x8;
typedef __attribute__((ext_vector_type(8))) unsigned short u16x8;
typedef __attribute__((ext_vector_type(4))) float f32x4;

#define LOG2E 1.4426950408889634f
#define C2T   2.8853900817779268f   // 2*log2(e)

// output element offsets (return order: logits, c_fin, h_fin, alphas)
#define OFF_C ((size_t)BB * LL * VV)
#define OFF_H (OFF_C + (size_t)BB * HH)
#define OFF_A (OFF_H + (size_t)BB * HH)

// ws byte offsets
#define WS_ENCT 0                    // 8,388,608 B u16 encT [b][h][e] C2T-prescaled
#define WS_HS   ((size_t)8388608)    // 524,288 B bf16
#define WS_GX   ((size_t)8912896)    // 4,194,304 B f32
#define WS_PAYU ((size_t)13107200)   // 532,480 B u64 [32][8][2][130]
#define WS_PAYG ((size_t)13639680)   // 262,144 B u64 [32][8][2][64]
#define WS_WT   ((size_t)13901824)   // 8,192,000 B u16 w_softT
#define WS_DFL  ((size_t)22093824)   // 4 B detect flag
#define WS_NEED ((size_t)22093828)

#define PAYU_WORDS (32 * 8 * 2 * 130)   // 66,560
#define PAYG_WORDS (32 * 8 * 2 * 64)    // 32,768
#define PAY_TOTAL  (PAYU_WORDS + PAYG_WORDS)   // 99,328

// mega-prep role ranges (256 threads per block)
#define RESET_BLKS ((PAY_TOTAL + 255) / 256)   // 388
#define GX_BLKS    128
#define ENC_BLKS   (16 * BB)                   // 512
#define TW_BLKS    ((VV / 32) * 4)             // 4000
#define PREP_BLKS  (RESET_BLKS + GX_BLKS + ENC_BLKS + TW_BLKS)

__device__ __forceinline__ float bf2f(u16 u) {
    union { unsigned int i; float f; } v; v.i = ((unsigned int)u) << 16; return v.f;
}
__device__ __forceinline__ u16 f2bf(float f) {
    union { float f; unsigned int i; } v; v.f = f;
    unsigned int x = v.i;
    return (u16)((x + 0x7FFFu + ((x >> 16) & 1u)) >> 16);
}
__device__ __forceinline__ float ldf(const void* p, size_t i, int f32) {
    if (f32) return ((const float*)p)[i];
    return bf2f(((const u16*)p)[i]);
}
__device__ __forceinline__ void stout(void* p, size_t i, float v, int f32) {
    if (f32) ((float*)p)[i] = v;
    else ((u16*)p)[i] = f2bf(v);
}
__device__ __forceinline__ float sigm(float x) {
    return __builtin_amdgcn_rcpf(1.f + __builtin_amdgcn_exp2f(-x * LOG2E));
}
__device__ __forceinline__ float tanh_fast(float x) {
    return 1.f - 2.f * __builtin_amdgcn_rcpf(__builtin_amdgcn_exp2f(x * C2T) + 1.f);
}

// ---- mega-prep: reset + detect + gatesx + encproj + w_soft transpose -----
// (proven correct in round 12)
__global__ __launch_bounds__(256) void megaprep_kernel(
    const int* __restrict__ sent, const void* __restrict__ w_emb,
    const void* __restrict__ w_lstm, const void* __restrict__ enc_out,
    const void* __restrict__ V, const void* __restrict__ w_soft,
    float* __restrict__ gx, u16* __restrict__ encT, u16* __restrict__ wT,
    u64* __restrict__ pay, int* __restrict__ flag)
{
    const int blk = blockIdx.x;
    const int tid = threadIdx.x;
    __shared__ float smem[16384];              // 64KB, aliased per role
    __shared__ int dcnt[4];

    if (blk < RESET_BLKS) {
        int i = blk * 256 + tid;
        if (i < PAY_TOTAL) pay[i] = 0ull;
        if (blk == 0) {
            float a = fabsf(bf2f((u16)(((const unsigned int*)w_emb)[tid] & 0xFFFFu)));
            unsigned long long m = __ballot(a > 1e-4f && a < 0.5f);
            if ((tid & 63) == 0) dcnt[tid >> 6] = __popcll(m);
            __syncthreads();
            if (tid == 0)
                *flag = (dcnt[0] + dcnt[1] + dcnt[2] + dcnt[3] > 128) ? 1 : 0;
        }
        return;
    }
    // inline detect for all compute roles (no cross-block dependency)
    float da = fabsf(bf2f((u16)(((const unsigned int*)w_emb)[tid] & 0xFFFFu)));
    unsigned long long dm = __ballot(da > 1e-4f && da < 0.5f);
    if ((tid & 63) == 0) dcnt[tid >> 6] = __popcll(dm);
    __syncthreads();
    const int isf32 = !(dcnt[0] + dcnt[1] + dcnt[2] + dcnt[3] > 128);
    __syncthreads();

    if (blk < RESET_BLKS + GX_BLKS) {
        int row0 = (blk - RESET_BLKS) * 16;
        float (*xr)[128] = (float(*)[128])smem;
        for (int i = tid; i < 2048; i += 256) {
            int r = i >> 7, col = i & 127;
            int id = sent[row0 + r];
            xr[r][col] = ldf(w_emb, (size_t)id * HH + col, isf32);
        }
        __syncthreads();
        int c0 = tid, c1 = tid + 256;
        float a0[16], a1[16];
        #pragma unroll
        for (int r = 0; r < 16; ++r) { a0[r] = 0.f; a1[r] = 0.f; }
        for (int kk = 0; kk < 128; ++kk) {
            float w0, w1;
            if (isf32) {
                w0 = ((const float*)w_lstm)[(size_t)kk * 512 + c0];
                w1 = ((const float*)w_lstm)[(size_t)kk * 512 + c1];
            } else {
                w0 = bf2f(((const u16*)w_lstm)[(size_t)kk * 512 + c0]);
                w1 = bf2f(((const u16*)w_lstm)[(size_t)kk * 512 + c1]);
            }
            #pragma unroll
            for (int r = 0; r < 16; ++r) {
                a0[r] += xr[r][kk] * w0;
                a1[r] += xr[r][kk] * w1;
            }
        }
        #pragma unroll
        for (int r = 0; r < 16; ++r) {
            gx[(size_t)(row0 + r) * 512 + c0] = a0[r];
            gx[(size_t)(row0 + r) * 512 + c1] = a1[r];
        }
        return;
    }
    if (blk < RESET_BLKS + GX_BLKS + ENC_BLKS) {
        // encT[b][h][e] = bf16(C2T * enc[b][e][:] . V_e[:][h])
        int idx = blk - RESET_BLKS - GX_BLKS;
        int b = idx >> 4;
        int e0 = (idx & 15) * 64;
        float (*ve)[128] = (float(*)[128])smem;
        for (int i = tid; i < HH * HH; i += 256)
            ve[i >> 7][i & 127] = ldf(V, i, isf32);
        __syncthreads();
        int e = e0 + (tid & 63);
        int hb = (tid >> 6) * 32;
        size_t rowbase = ((size_t)b * EE + e) * HH;
        float acc[32];
        #pragma unroll
        for (int i = 0; i < 32; ++i) acc[i] = 0.f;
        for (int k0 = 0; k0 < HH; k0 += 16) {
            float ef[16];
            #pragma unroll
            for (int i = 0; i < 16; ++i) ef[i] = ldf(enc_out, rowbase + k0 + i, isf32);
            #pragma unroll
            for (int hh = 0; hh < 32; ++hh) {
                float a = acc[hh];
                #pragma unroll
                for (int kk = 0; kk < 16; ++kk)
                    a += ef[kk] * ve[k0 + kk][hb + hh];
                acc[hh] = a;
            }
        }
        u16* outp = encT + ((size_t)b * HH) * EE + e;   // [b][h][e]
        #pragma unroll
        for (int hh = 0; hh < 32; ++hh)
            outp[(size_t)(hh + hb) * EE] = f2bf(acc[hh] * C2T);
        return;
    }
    // w_softT = transpose(w_soft) : (VV, HH) bf16
    {
        int idx = blk - RESET_BLKS - GX_BLKS - ENC_BLKS;
        int n0 = (idx >> 2) * 32;
        int k0 = (idx & 3) * 32;
        u16 (*tile)[33] = (u16(*)[33])smem;
        int tx = tid & 31, ty0 = tid >> 5;
        #pragma unroll
        for (int i = 0; i < 4; ++i) {
            int ty = ty0 + i * 8;
            tile[ty][tx] = f2bf(ldf(w_soft, (size_t)(k0 + ty) * VV + n0 + tx, isf32));
        }
        __syncthreads();
        #pragma unroll
        for (int i = 0; i < 4; ++i) {
            int ty = ty0 + i * 8;
            wT[(size_t)(n0 + ty) * HH + k0 + tx] = tile[tx][ty];
        }
    }
}

// ---- cooperative scan: EXACT round-8 structure (proven 531 us) -----------
// 8 blocks per batch, e-slice of 128 per block. Phase A split 8 ways with
// gate-slice exchange; D from bf16 encT in LDS; F from f32 enc in LDS;
// C from L2. Two relaxed tag-packed u64 exchanges per step. 10 barriers.
// Only delta vs round 8: encT arrives pre-converted to bf16 (same values).
__global__ __launch_bounds__(1024) void scan_kernel(
    const void* __restrict__ init_c, const void* __restrict__ init_h,
    const void* __restrict__ enc_out, const void* __restrict__ w_lstm,
    const void* __restrict__ V, const u16* __restrict__ encTg16,
    const float* __restrict__ gx, u16* __restrict__ hs_bf,
    void* __restrict__ out, u64* __restrict__ payu, u64* __restrict__ payg,
    const int* __restrict__ flagp)
{
    const int isf32 = !flagp[0];
    const int bid = blockIdx.x;
    const int b = bid & 31, k = bid >> 5;      // 8 partners, same XCD
    const int tid = threadIdx.x;

    __shared__ u16   encTl16[128][128];        // 32KB bf16, C2T-prescaled [h][e]
    __shared__ float encF[128][128];           // 64KB f32 enc slice [e][h]
    __shared__ u16   wrec16[64 * 128];         // 16KB bf16 [col_local][k]
    __shared__ float gall[512];
    __shared__ float harr[128], cst[128], hnew[128], hvC[128];
    __shared__ float dred[8][128];
    __shared__ float sc[128];
    __shared__ float exch[8][130];
    __shared__ float redw[2], redw2[2];
    __shared__ float m_s, s_s;

    // ---- one-time staging ----
    for (int i = tid; i < 128 * 128; i += 1024) {       // encT slice (bf16 copy)
        int h = i >> 7, e = i & 127;
        encTl16[h][e] = encTg16[(size_t)(b * 128 + h) * EE + k * 128 + e];
    }
    for (int i = tid; i < 128 * 128; i += 1024) {       // enc slice -> f32
        int e = i >> 7, hh = i & 127;
        encF[e][hh] = ldf(enc_out, ((size_t)b * EE + k * 128 + e) * HH + hh, isf32);
    }
    for (int i = tid; i < 64 * 128; i += 1024) {        // w_rec col slice -> bf16
        int c = i >> 7, kk = i & 127;
        wrec16[c * 128 + kk] = f2bf(ldf(w_lstm, (size_t)(HH + kk) * 512 + k * 64 + c, isf32));
    }
    if (tid < 128) {
        cst[tid]  = ldf(init_c, (size_t)b * HH + tid, isf32);
        harr[tid] = ldf(init_h, (size_t)b * HH + tid, isf32);
    }
    __syncthreads();

    u64* mypu = payu + (size_t)(b * 8 + k) * 2 * 130;
    u64* mypg = payg + (size_t)(b * 8 + k) * 2 * 64;

    for (int t = 0; t < LL; ++t) {
        const unsigned int want = (unsigned int)(t + 1);
        // prefetch gx words for B
        float g0 = 0.f, g1 = 0.f, g2 = 0.f, g3 = 0.f;
        if (tid < 128) {
            const float* gxr = gx + (size_t)(b * LL + t) * 512;
            g0 = gxr[tid]; g1 = gxr[128 + tid]; g2 = gxr[256 + tid]; g3 = gxr[384 + tid];
        }
        // A: this block's 64 gate cols; 16 lanes per col, shfl butterfly
        {
            int colL = tid >> 4, kc = tid & 15;
            const bf16x8 wv = *(const bf16x8*)&wrec16[colL * 128 + kc * 8];
            float acc = 0.f;
            #pragma unroll
            for (int j = 0; j < 8; ++j)
                acc = __builtin_fmaf(harr[kc * 8 + j], bf2f((u16)wv[j]), acc);
            acc += __shfl_xor(acc, 1);
            acc += __shfl_xor(acc, 2);
            acc += __shfl_xor(acc, 4);
            acc += __shfl_xor(acc, 8);
            if (kc == 0) {
                gall[(k << 6) + colL] = acc;
                union { float f; unsigned int u; } cv; cv.f = acc;
                u64 w = ((u64)want << 32) | (u64)cv.u;
                __hip_atomic_store(&mypg[(size_t)(t & 1) * 64 + colL], w,
                                   __ATOMIC_RELAXED, __HIP_MEMORY_SCOPE_AGENT);
            }
        }
        // poll partners' gate slices (448 words)
        if (tid < 448) {
            int qq = tid >> 6;
            int q = qq + (qq >= k ? 1 : 0);
            int idx = tid & 63;
            const u64* qp = payg + ((size_t)(b * 8 + q) * 2 + (t & 1)) * 64 + idx;
            u64 w = __hip_atomic_load(qp, __ATOMIC_RELAXED, __HIP_MEMORY_SCOPE_AGENT);
            int cnt = 0;
            while ((unsigned int)(w >> 32) != want) {
                __builtin_amdgcn_s_sleep(1);
                w = __hip_atomic_load(qp, __ATOMIC_RELAXED, __HIP_MEMORY_SCOPE_AGENT);
                if (++cnt > (1 << 20)) break;   // fail visibly, never hang
            }
            union { unsigned int u; float f; } cv; cv.u = (unsigned int)(w & 0xFFFFFFFFu);
            gall[q * 64 + idx] = cv.f;
        }
        __syncthreads();                                   // (1)
        // B: LSTM cell (gall identical across replicas)
        if (tid < 128) {
            float gi = g0 + gall[tid];
            float gf = g1 + gall[128 + tid];
            float go = g2 + gall[256 + tid];
            float gg = g3 + gall[384 + tid];
            float c_new = sigm(gf) * cst[tid] + sigm(gi) * tanh_fast(gg);
            cst[tid] = c_new;
            hnew[tid] = sigm(go) * tanh_fast(c_new);
        }
        __syncthreads();                                   // (2)
        // C: hv[h] = h_new . V_h[:,h] (L2-hot 64KB, shared by whole XCD)
        {
            int h = tid & 127, jc = tid >> 7;
            float p = 0.f;
            if (isf32) {
                const float* vp = (const float*)V + (size_t)(HH + jc * 16) * HH + h;
                #pragma unroll
                for (int j = 0; j < 16; ++j)
                    p += hnew[jc * 16 + j] * vp[(size_t)j * HH];
            } else {
                const u16* vp = (const u16*)V + (size_t)(HH + jc * 16) * HH + h;
                #pragma unroll
                for (int j = 0; j < 16; ++j)
                    p += hnew[jc * 16 + j] * bf2f(vp[(size_t)j * HH]);
            }
            dred[jc][h] = p;
        }
        __syncthreads();                                   // (3)
        if (tid < 128) {
            float v = 0.f;
            #pragma unroll
            for (int s = 0; s < 8; ++s) v += dred[s][tid];
            hvC[tid] = v * C2T;
        }
        __syncthreads();                                   // (4)
        // D: partial tanh sums over own 128-e slice (LDS bf16)
        {
            int e = tid & 127, hc = tid >> 7;
            float sumr = 0.f;
            #pragma unroll
            for (int j = 0; j < 16; ++j) {
                int h = hc * 16 + j;
                float a = bf2f(encTl16[h][e]) + hvC[h];
                sumr += __builtin_amdgcn_rcpf(__builtin_amdgcn_exp2f(a) + 1.f);
            }
            dred[hc][e] = sumr;
        }
        __syncthreads();                                   // (5)
        // E: local scores + local softmax stats
        float s_e = 0.f, p_reg = 0.f;
        if (tid < 128) {
            float sr = 0.f;
            #pragma unroll
            for (int s = 0; s < 8; ++s) sr += dred[s][tid];
            s_e = 128.f - 2.f * sr;
            float m = s_e;
            #pragma unroll
            for (int off = 32; off; off >>= 1) m = fmaxf(m, __shfl_xor(m, off));
            if ((tid & 63) == 0) redw[tid >> 6] = m;
        }
        __syncthreads();                                   // (6)
        if (tid < 128) {
            float mloc = fmaxf(redw[0], redw[1]);
            p_reg = __builtin_amdgcn_exp2f((s_e - mloc) * LOG2E);
            sc[tid] = p_reg;
            float s = p_reg;
            #pragma unroll
            for (int off = 32; off; off >>= 1) s += __shfl_xor(s, off);
            if ((tid & 63) == 0) redw2[tid >> 6] = s;
            if (tid == 0) m_s = mloc;
        }
        __syncthreads();                                   // (7)
        if (tid == 0) s_s = redw2[0] + redw2[1];
        // F: partial unnormalized context from LDS enc slice (f32, exact)
        {
            int h = tid & 127, ec = tid >> 7;
            float p = 0.f;
            #pragma unroll
            for (int j = 0; j < 16; ++j)
                p += sc[ec * 16 + j] * encF[ec * 16 + j][h];
            dred[ec][h] = p;
        }
        __syncthreads();                                   // (8)
        // reduce U and publish straight from registers
        float Uv = 0.f;
        if (tid < 128) {
            #pragma unroll
            for (int s = 0; s < 8; ++s) Uv += dred[s][tid];
        }
        {
            u64* pp = mypu + (size_t)(t & 1) * 130;
            if (tid < 130) {
                float val = (tid < 128) ? Uv : ((tid == 128) ? m_s : s_s);
                union { float f; unsigned int u; } cv; cv.f = val;
                u64 w = ((u64)want << 32) | (u64)cv.u;
                __hip_atomic_store(&pp[tid], w, __ATOMIC_RELAXED, __HIP_MEMORY_SCOPE_AGENT);
                exch[k][tid] = val;
            }
        }
        // poll partners' U payloads (910 threads, one word each)
        if (tid < 910) {
            int qq = tid / 130;
            int q = qq + (qq >= k ? 1 : 0);
            int idx = tid - qq * 130;
            const u64* qp = payu + ((size_t)(b * 8 + q) * 2 + (t & 1)) * 130 + idx;
            u64 w = __hip_atomic_load(qp, __ATOMIC_RELAXED, __HIP_MEMORY_SCOPE_AGENT);
            int cnt = 0;
            while ((unsigned int)(w >> 32) != want) {
                __builtin_amdgcn_s_sleep(1);
                w = __hip_atomic_load(qp, __ATOMIC_RELAXED, __HIP_MEMORY_SCOPE_AGENT);
                if (++cnt > (1 << 20)) break;   // fail visibly, never hang
            }
            union { unsigned int u; float f; } cv; cv.u = (unsigned int)(w & 0xFFFFFFFFu);
            exch[q][idx] = cv.f;
        }
        __syncthreads();                                   // (9)
        // combine in canonical order -> bit-identical context in all replicas
        if (tid < 128) {
            float M = exch[0][128];
            #pragma unroll
            for (int q = 1; q < 8; ++q) M = fmaxf(M, exch[q][128]);
            float St = 0.f, ch = 0.f;
            #pragma unroll
            for (int q = 0; q < 8; ++q) {
                float w = __builtin_amdgcn_exp2f((exch[q][128] - M) * LOG2E);
                St += w * exch[q][129];
                ch += w * exch[q][tid];
            }
            float rS = __builtin_amdgcn_rcpf(St);
            float ctx = ch * rS;
            harr[tid] = ctx;
            float al = p_reg * __builtin_amdgcn_exp2f((m_s - M) * LOG2E) * rS;
            stout(out, OFF_A + (size_t)(b * LL + t) * EE + k * 128 + tid, al, isf32);
            if (k == 0) {
                hs_bf[(size_t)(b * LL + t) * HH + tid] = f2bf(ctx);
                if (t == LL - 1) {
                    stout(out, OFF_H + (size_t)b * HH + tid, ctx, isf32);
                    stout(out, OFF_C + (size_t)b * HH + tid, cst[tid], isf32);
                }
            }
        }
        __syncthreads();                                   // (10)
    }
}

// ---- logits = hs @ w_soft : MFMA bf16 ------------------------------------
__global__ __launch_bounds__(256) void logits_gemm(
    const u16* __restrict__ hs, const u16* __restrict__ wT,
    void* __restrict__ out, const int* __restrict__ flagp)
{
    int isf32 = !flagp[0];
    int n0 = blockIdx.x * 32;
    int m0 = (blockIdx.y * 4 + (threadIdx.x >> 6)) * 32;
    int lane = threadIdx.x & 63;
    int lr = lane & 15, lh = lane >> 4;
    f32x4 acc00 = {0.f, 0.f, 0.f, 0.f}, acc01 = acc00, acc10 = acc00, acc11 = acc00;
    const u16* a0p = hs + (size_t)(m0 + lr) * HH + lh * 8;
    const u16* a1p = a0p + (size_t)16 * HH;
    const u16* b0p = wT + (size_t)(n0 + lr) * HH + lh * 8;
    const u16* b1p = b0p + (size_t)16 * HH;
    #pragma unroll
    for (int ks = 0; ks < 4; ++ks) {
        bf16x8 a0 = *(const bf16x8*)(a0p + ks * 32);
        bf16x8 a1 = *(const bf16x8*)(a1p + ks * 32);
        bf16x8 b0 = *(const bf16x8*)(b0p + ks * 32);
        bf16x8 b1 = *(const bf16x8*)(b1p + ks * 32);
        acc00 = __builtin_amdgcn_mfma_f32_16x16x32_bf16(a0, b0, acc00, 0, 0, 0);
        acc01 = __builtin_amdgcn_mfma_f32_16x16x32_bf16(a0, b1, acc01, 0, 0, 0);
        acc10 = __builtin_amdgcn_mfma_f32_16x16x32_bf16(a1, b0, acc10, 0, 0, 0);
        acc11 = __builtin_amdgcn_mfma_f32_16x16x32_bf16(a1, b1, acc11, 0, 0, 0);
    }
    size_t base0 = (size_t)(m0 + lh * 4) * VV + n0;
    size_t base1 = (size_t)(m0 + 16 + lh * 4) * VV + n0;
    #pragma unroll
    for (int r = 0; r < 4; ++r) {
        stout(out, base0 + (size_t)r * VV + lr,      acc00[r], isf32);
        stout(out, base0 + (size_t)r * VV + 16 + lr, acc01[r], isf32);
        stout(out, base1 + (size_t)r * VV + lr,      acc10[r], isf32);
        stout(out, base1 + (size_t)r * VV + 16 + lr, acc11[r], isf32);
    }
}

extern "C" void kernel_launch(void* const* d_in, const int* in_sizes, int n_in,
                              void* d_out, int out_size, void* d_ws, size_t ws_size,
                              hipStream_t stream)
{
    (void)in_sizes; (void)n_in; (void)out_size;
    if (ws_size < WS_NEED) return;

    const int* sent     = (const int*)d_in[0];
    const void* init_c  = d_in[1];
    const void* init_h  = d_in[2];
    const void* enc_out = d_in[3];
    const void* w_emb   = d_in[4];
    const void* w_lstm  = d_in[5];
    const void* w_soft  = d_in[6];
    const void* V       = d_in[7];

    char* ws = (char*)d_ws;
    u16*   encT  = (u16*)(ws + WS_ENCT);
    u16*   hs    = (u16*)(ws + WS_HS);
    float* gx    = (float*)(ws + WS_GX);
    u64*   payu  = (u64*)(ws + WS_PAYU);
    u64*   payg  = (u64*)(ws + WS_PAYG);
    u16*   wT    = (u16*)(ws + WS_WT);
    int*   dflag = (int*)(ws + WS_DFL);

    hipLaunchKernelGGL(megaprep_kernel, dim3(PREP_BLKS), dim3(256), 0, stream,
                       sent, w_emb, w_lstm, enc_out, V, w_soft,
                       gx, encT, wT, payu, dflag);

    {
        const void* a0 = init_c; const void* a1 = init_h; const void* a2 = enc_out;
        const void* a3 = w_lstm; const void* a4 = V; const u16* a5 = encT;
        const float* a6 = gx; u16* a7 = hs; void* a8 = d_out;
        u64* a9 = payu; u64* a10 = payg; const int* a11 = dflag;
        void* args[] = {&a0, &a1, &a2, &a3, &a4, &a5, &a6, &a7, &a8, &a9, &a10, &a11};
        hipLaunchCooperativeKernel(scan_kernel, dim3(256), dim3(1024), args, 0, stream);
    }

    hipLaunchKernelGGL(logits_gemm, dim3(VV / 32, 16), dim3(256), 0, stream, hs, wT, d_out, dflag);
}